// Round 1
// baseline (1243.620 us; speedup 1.0000x reference)
//
#include <hip/hip_runtime.h>

typedef unsigned short ushort_t;
typedef __bf16 bf16x8 __attribute__((ext_vector_type(8)));
typedef float f32x4 __attribute__((ext_vector_type(4)));
typedef unsigned short u16x8 __attribute__((ext_vector_type(8)));
typedef unsigned short u16x4 __attribute__((ext_vector_type(4)));

#define MFMA16(a, b, c) __builtin_amdgcn_mfma_f32_16x16x32_bf16(a, b, c, 0, 0, 0)

#define DIM 192
#define HEADS 6
#define HD 32
#define GROUPS 8
#define CPG 24          // channels per group
#define HID 768
#define NWIN 4096       // 4 * 32 * 32
#define GN_N 1572864    // 24 * 256 * 256
#define SCALE 0.17677669529663687f

__device__ __forceinline__ ushort_t f2b(float f) {
  union { float f; unsigned int u; } v; v.f = f;
  unsigned int r = v.u + 0x7FFFu + ((v.u >> 16) & 1u);
  return (ushort_t)(r >> 16);
}
__device__ __forceinline__ float b2f(ushort_t u) {
  union { unsigned int u; float f; } v; v.u = ((unsigned int)u) << 16;
  return v.f;
}

// ---------------- weight transpose + bf16 convert: out[n][k] = in[k][n] ----
__global__ __launch_bounds__(256) void transpose_w(const float* __restrict__ in,
                                                   ushort_t* __restrict__ out,
                                                   int K, int N) {
  int id = blockIdx.x * 256 + threadIdx.x;
  if (id >= K * N) return;
  int n = id / K, k = id - n * K;
  out[id] = f2b(in[k * N + n]);
}

// ---------------- GroupNorm stats, stage 1 (fp32 input) --------------------
__global__ __launch_bounds__(256) void gn_stats1_f32(const float* __restrict__ x,
                                                     float* __restrict__ partial) {
  int bid = blockIdx.x;           // 32 * 64
  int sg = bid >> 6, chunk = bid & 63;
  const float* p = x + (size_t)sg * GN_N + (size_t)chunk * 24576;
  int tid = threadIdx.x;
  float s = 0.f, s2 = 0.f;
#pragma unroll
  for (int i = 0; i < 24; ++i) {
    float4 v = *(const float4*)(p + (size_t)(i * 256 + tid) * 4);
    s += v.x + v.y + v.z + v.w;
    s2 += v.x * v.x + v.y * v.y + v.z * v.z + v.w * v.w;
  }
  for (int m = 1; m < 64; m <<= 1) { s += __shfl_xor(s, m); s2 += __shfl_xor(s2, m); }
  __shared__ float red[8];
  int wv = tid >> 6;
  if ((tid & 63) == 0) { red[wv * 2] = s; red[wv * 2 + 1] = s2; }
  __syncthreads();
  if (tid == 0) {
    float a = 0.f, b = 0.f;
    for (int i = 0; i < 4; ++i) { a += red[i * 2]; b += red[i * 2 + 1]; }
    partial[bid * 2] = a; partial[bid * 2 + 1] = b;
  }
}

// ---------------- GroupNorm stats, stage 1 (bf16 input) --------------------
__global__ __launch_bounds__(256) void gn_stats1_bf16(const ushort_t* __restrict__ x,
                                                      float* __restrict__ partial) {
  int bid = blockIdx.x;
  int sg = bid >> 6, chunk = bid & 63;
  const ushort_t* p = x + (size_t)sg * GN_N + (size_t)chunk * 24576;
  int tid = threadIdx.x;
  float s = 0.f, s2 = 0.f;
#pragma unroll
  for (int i = 0; i < 12; ++i) {
    u16x8 v = *(const u16x8*)(p + (size_t)(i * 256 + tid) * 8);
#pragma unroll
    for (int t = 0; t < 8; ++t) { float f = b2f(v[t]); s += f; s2 += f * f; }
  }
  for (int m = 1; m < 64; m <<= 1) { s += __shfl_xor(s, m); s2 += __shfl_xor(s2, m); }
  __shared__ float red[8];
  int wv = tid >> 6;
  if ((tid & 63) == 0) { red[wv * 2] = s; red[wv * 2 + 1] = s2; }
  __syncthreads();
  if (tid == 0) {
    float a = 0.f, b = 0.f;
    for (int i = 0; i < 4; ++i) { a += red[i * 2]; b += red[i * 2 + 1]; }
    partial[bid * 2] = a; partial[bid * 2 + 1] = b;
  }
}

// ---------------- GroupNorm stats, stage 2 ---------------------------------
__global__ __launch_bounds__(64) void gn_stats2(const float* __restrict__ partial,
                                                float* __restrict__ stats) {
  int sg = blockIdx.x;
  int lane = threadIdx.x;
  float s = partial[(sg * 64 + lane) * 2];
  float s2 = partial[(sg * 64 + lane) * 2 + 1];
  for (int m = 1; m < 64; m <<= 1) { s += __shfl_xor(s, m); s2 += __shfl_xor(s2, m); }
  if (lane == 0) {
    const float invN = 1.0f / (float)GN_N;
    float mean = s * invN;
    float var = s2 * invN - mean * mean;
    stats[sg * 2] = mean;
    stats[sg * 2 + 1] = rsqrtf(var + 1e-5f);
  }
}

// ---------------- fused window attention -----------------------------------
// one block per window, 6 waves (384 threads); wave w owns head w in attention
__global__ __launch_bounds__(384, 1) void attn_kernel(
    const float* __restrict__ x,
    const ushort_t* __restrict__ qkvT, const float* __restrict__ qkv_b,
    const ushort_t* __restrict__ projT, const float* __restrict__ proj_b,
    const float* __restrict__ stats1,
    const float* __restrict__ n1w, const float* __restrict__ n1b,
    ushort_t* __restrict__ x_mid) {
  int w = blockIdx.x;
  int b = w >> 10, wh = (w >> 5) & 31, ww = w & 31;
  int tid = threadIdx.x;
  int wave = tid >> 6, lane = tid & 63;
  int p = lane & 15, q = lane >> 4;

  __shared__ ushort_t tile[64][200];    // xn tile -> O tile -> proj-out tile
  __shared__ ushort_t qkP[6][5120];     // per head: q[64][40] | k[64][40], later P[64][72]
  __shared__ ushort_t vT[6][2304];      // per head: v^T [32][72]

  // ---- phase 0: gather + groupnorm + roll into tile[token][c] ----
  for (int idx = tid; idx < 1536; idx += 384) {
    int c = idx >> 3, i = idx & 7;
    int g = c / CPG;
    float mean = stats1[(b * 8 + g) * 2], rstd = stats1[(b * 8 + g) * 2 + 1];
    float gw = n1w[c] * rstd;
    float gb = n1b[c] - mean * gw;
    int py = ((wh << 3) + i + 4) & 255;
    const float* src = x + (((size_t)(b * DIM + c)) << 16) + (py << 8);
    int px0 = (ww << 3) + 4;
    int px1 = (px0 + 4) & 255;
    float4 ra = *(const float4*)(src + px0);
    float4 rb = *(const float4*)(src + px1);
    int t0 = i * 8;
    tile[t0 + 0][c] = f2b(ra.x * gw + gb);
    tile[t0 + 1][c] = f2b(ra.y * gw + gb);
    tile[t0 + 2][c] = f2b(ra.z * gw + gb);
    tile[t0 + 3][c] = f2b(ra.w * gw + gb);
    tile[t0 + 4][c] = f2b(rb.x * gw + gb);
    tile[t0 + 5][c] = f2b(rb.y * gw + gb);
    tile[t0 + 6][c] = f2b(rb.z * gw + gb);
    tile[t0 + 7][c] = f2b(rb.w * gw + gb);
  }
  __syncthreads();

  // ---- phase 1: qkv GEMM, wave handles 96 output cols ----
  {
    int colbase = wave * 96;
    for (int nt = 0; nt < 6; ++nt) {
      int col = colbase + nt * 16 + p;
      f32x4 acc[4];
#pragma unroll
      for (int mt = 0; mt < 4; ++mt) acc[mt] = (f32x4){0.f, 0.f, 0.f, 0.f};
#pragma unroll
      for (int ks = 0; ks < 6; ++ks) {
        int k0 = ks * 32 + q * 8;
        bf16x8 bfr = *(const bf16x8*)(qkvT + (size_t)col * DIM + k0);
#pragma unroll
        for (int mt = 0; mt < 4; ++mt) {
          bf16x8 afr = *(const bf16x8*)&tile[mt * 16 + p][k0];
          acc[mt] = MFMA16(afr, bfr, acc[mt]);
        }
      }
      float bias = qkv_b[col];
      int sec = col / DIM;
      int hc = col - sec * DIM;
      int h = hc >> 5, d = hc & 31;
#pragma unroll
      for (int mt = 0; mt < 4; ++mt)
#pragma unroll
        for (int r = 0; r < 4; ++r) {
          int token = mt * 16 + q * 4 + r;
          float v = acc[mt][r] + bias;
          if (sec == 0)      qkP[h][token * 40 + d] = f2b(v * SCALE);
          else if (sec == 1) qkP[h][2560 + token * 40 + d] = f2b(v);
          else               vT[h][d * 72 + token] = f2b(v);
        }
    }
  }
  __syncthreads();

  // ---- phase 2: attention, wave = head ----
  {
    int h = wave;
    const ushort_t* qh = &qkP[h][0];
    const ushort_t* kh = &qkP[h][2560];
    int k0 = q * 8;
    bf16x8 afr[4], bfr[4];
#pragma unroll
    for (int mt = 0; mt < 4; ++mt) afr[mt] = *(const bf16x8*)&qh[(mt * 16 + p) * 40 + k0];
#pragma unroll
    for (int nt = 0; nt < 4; ++nt) bfr[nt] = *(const bf16x8*)&kh[(nt * 16 + p) * 40 + k0];
    f32x4 s[4][4];
#pragma unroll
    for (int mt = 0; mt < 4; ++mt)
#pragma unroll
      for (int nt = 0; nt < 4; ++nt) {
        s[mt][nt] = (f32x4){0.f, 0.f, 0.f, 0.f};
        s[mt][nt] = MFMA16(afr[mt], bfr[nt], s[mt][nt]);
      }
    // softmax over 64 cols; lane's rows: mt*16 + q*4 + r, cols nt*16 + p
    ushort_t* Ph = &qkP[h][0];
#pragma unroll
    for (int mt = 0; mt < 4; ++mt)
#pragma unroll
      for (int r = 0; r < 4; ++r) {
        float m = fmaxf(fmaxf(s[mt][0][r], s[mt][1][r]), fmaxf(s[mt][2][r], s[mt][3][r]));
        for (int msk = 1; msk < 16; msk <<= 1) m = fmaxf(m, __shfl_xor(m, msk));
        float e0 = __expf(s[mt][0][r] - m);
        float e1 = __expf(s[mt][1][r] - m);
        float e2 = __expf(s[mt][2][r] - m);
        float e3 = __expf(s[mt][3][r] - m);
        float sum = e0 + e1 + e2 + e3;
        for (int msk = 1; msk < 16; msk <<= 1) sum += __shfl_xor(sum, msk);
        float inv = 1.0f / sum;
        int token = mt * 16 + q * 4 + r;
        Ph[token * 72 + 0 * 16 + p] = f2b(e0 * inv);
        Ph[token * 72 + 1 * 16 + p] = f2b(e1 * inv);
        Ph[token * 72 + 2 * 16 + p] = f2b(e2 * inv);
        Ph[token * 72 + 3 * 16 + p] = f2b(e3 * inv);
      }
    // PV: O = P(64x64) @ V(64x32)
    f32x4 o[4][2];
#pragma unroll
    for (int mt = 0; mt < 4; ++mt)
#pragma unroll
      for (int nt = 0; nt < 2; ++nt) o[mt][nt] = (f32x4){0.f, 0.f, 0.f, 0.f};
#pragma unroll
    for (int ks = 0; ks < 2; ++ks) {
      int kk = ks * 32 + q * 8;
      bf16x8 bv[2];
#pragma unroll
      for (int nt = 0; nt < 2; ++nt) bv[nt] = *(const bf16x8*)&vT[h][(nt * 16 + p) * 72 + kk];
#pragma unroll
      for (int mt = 0; mt < 4; ++mt) {
        bf16x8 ap = *(const bf16x8*)&Ph[(mt * 16 + p) * 72 + kk];
#pragma unroll
        for (int nt = 0; nt < 2; ++nt) o[mt][nt] = MFMA16(ap, bv[nt], o[mt][nt]);
      }
    }
    // write O into tile[token][h*32+d]
#pragma unroll
    for (int mt = 0; mt < 4; ++mt)
#pragma unroll
      for (int nt = 0; nt < 2; ++nt)
#pragma unroll
        for (int r = 0; r < 4; ++r)
          tile[mt * 16 + q * 4 + r][h * 32 + nt * 16 + p] = f2b(o[mt][nt][r]);
  }
  __syncthreads();

  // ---- phase 3: proj GEMM (wave handles 32 cols) ----
  {
    int colbase = wave * 32;
    f32x4 pr[4][2];
#pragma unroll
    for (int mt = 0; mt < 4; ++mt)
#pragma unroll
      for (int nt = 0; nt < 2; ++nt) pr[mt][nt] = (f32x4){0.f, 0.f, 0.f, 0.f};
#pragma unroll
    for (int ks = 0; ks < 6; ++ks) {
      int k0 = ks * 32 + q * 8;
      bf16x8 bfr[2];
#pragma unroll
      for (int nt = 0; nt < 2; ++nt)
        bfr[nt] = *(const bf16x8*)(projT + (size_t)(colbase + nt * 16 + p) * DIM + k0);
#pragma unroll
      for (int mt = 0; mt < 4; ++mt) {
        bf16x8 afr = *(const bf16x8*)&tile[mt * 16 + p][k0];
#pragma unroll
        for (int nt = 0; nt < 2; ++nt) pr[mt][nt] = MFMA16(afr, bfr[nt], pr[mt][nt]);
      }
    }
    __syncthreads();   // everyone done reading tile
#pragma unroll
    for (int mt = 0; mt < 4; ++mt)
#pragma unroll
      for (int nt = 0; nt < 2; ++nt) {
        int col = colbase + nt * 16 + p;
        float bias = proj_b[col];
#pragma unroll
        for (int r = 0; r < 4; ++r)
          tile[mt * 16 + q * 4 + r][col] = f2b(pr[mt][nt][r] + bias);
      }
  }
  __syncthreads();

  // ---- epilogue: residual 1 -> x_mid (bf16), with inverse roll ----
  for (int idx = tid; idx < 1536; idx += 384) {
    int c = idx >> 3, i = idx & 7;
    int py = ((wh << 3) + i + 4) & 255;
    size_t base = (((size_t)(b * DIM + c)) << 16) + (py << 8);
    const float* src = x + base;
    ushort_t* dst = x_mid + base;
    int px0 = (ww << 3) + 4;
    int px1 = (px0 + 4) & 255;
    float4 ra = *(const float4*)(src + px0);
    float4 rb = *(const float4*)(src + px1);
    int t0 = i * 8;
    u16x4 va, vb;
    va[0] = f2b(ra.x + b2f(tile[t0 + 0][c]));
    va[1] = f2b(ra.y + b2f(tile[t0 + 1][c]));
    va[2] = f2b(ra.z + b2f(tile[t0 + 2][c]));
    va[3] = f2b(ra.w + b2f(tile[t0 + 3][c]));
    vb[0] = f2b(rb.x + b2f(tile[t0 + 4][c]));
    vb[1] = f2b(rb.y + b2f(tile[t0 + 5][c]));
    vb[2] = f2b(rb.z + b2f(tile[t0 + 6][c]));
    vb[3] = f2b(rb.w + b2f(tile[t0 + 7][c]));
    *(u16x4*)(dst + px0) = va;
    *(u16x4*)(dst + px1) = vb;
  }
}

// ---------------- fused GN2 + MLP + residual2 ------------------------------
// one block per 64 consecutive pixels in a row; 4 waves (256 threads)
__global__ __launch_bounds__(256) void mlp_kernel(
    const ushort_t* __restrict__ x_mid,
    const ushort_t* __restrict__ w1T, const float* __restrict__ b1,
    const ushort_t* __restrict__ w2T, const float* __restrict__ b2,
    const float* __restrict__ stats2,
    const float* __restrict__ n2w, const float* __restrict__ n2b,
    float* __restrict__ out) {
  int bid = blockIdx.x;
  int b = bid >> 10, y = (bid >> 2) & 255, xq = bid & 3;
  int x0 = xq * 64;
  int tid = threadIdx.x;
  int wave = tid >> 6, lane = tid & 63;
  int p = lane & 15, q = lane >> 4;

  __shared__ ushort_t xn[64][200];   // xn tile, later mlp-out staging
  __shared__ ushort_t hb[64][72];    // hidden chunk

  for (int idx = tid; idx < DIM * 8; idx += 256) {
    int c = idx >> 3, c8 = (idx & 7) * 8;
    int g = c / CPG;
    float mean = stats2[(b * 8 + g) * 2], rstd = stats2[(b * 8 + g) * 2 + 1];
    float gw = n2w[c] * rstd;
    float gb = n2b[c] - mean * gw;
    u16x8 v = *(const u16x8*)(x_mid + (((size_t)(b * DIM + c)) << 16) + (y << 8) + x0 + c8);
#pragma unroll
    for (int t = 0; t < 8; ++t) xn[c8 + t][c] = f2b(b2f(v[t]) * gw + gb);
  }
  __syncthreads();

  f32x4 accO[4][3];
#pragma unroll
  for (int mt = 0; mt < 4; ++mt)
#pragma unroll
    for (int nt = 0; nt < 3; ++nt) accO[mt][nt] = (f32x4){0.f, 0.f, 0.f, 0.f};

  for (int ch = 0; ch < 12; ++ch) {
    // GEMM1: hidden chunk of 64 cols; wave handles 16
    int hcol = ch * 64 + wave * 16 + p;
    f32x4 a1[4];
#pragma unroll
    for (int mt = 0; mt < 4; ++mt) a1[mt] = (f32x4){0.f, 0.f, 0.f, 0.f};
#pragma unroll
    for (int ks = 0; ks < 6; ++ks) {
      int k0 = ks * 32 + q * 8;
      bf16x8 bfr = *(const bf16x8*)(w1T + (size_t)hcol * DIM + k0);
#pragma unroll
      for (int mt = 0; mt < 4; ++mt) {
        bf16x8 afr = *(const bf16x8*)&xn[mt * 16 + p][k0];
        a1[mt] = MFMA16(afr, bfr, a1[mt]);
      }
    }
    float bias = b1[hcol];
    if (ch) __syncthreads();     // previous chunk's GEMM2 readers done
#pragma unroll
    for (int mt = 0; mt < 4; ++mt)
#pragma unroll
      for (int r = 0; r < 4; ++r) {
        float v = a1[mt][r] + bias;
        v = 0.5f * v * (1.0f + erff(v * 0.70710678118654752f));
        hb[mt * 16 + q * 4 + r][wave * 16 + p] = f2b(v);
      }
    __syncthreads();
    // GEMM2: accO += gelu(h) @ W2[chunk,:]; wave handles 48 out cols
#pragma unroll
    for (int ks = 0; ks < 2; ++ks) {
      int k0 = ks * 32 + q * 8;
#pragma unroll
      for (int mt = 0; mt < 4; ++mt) {
        bf16x8 afr = *(const bf16x8*)&hb[mt * 16 + p][k0];
#pragma unroll
        for (int nt = 0; nt < 3; ++nt) {
          bf16x8 bfr = *(const bf16x8*)(w2T + (size_t)(wave * 48 + nt * 16 + p) * HID + ch * 64 + k0);
          accO[mt][nt] = MFMA16(afr, bfr, accO[mt][nt]);
        }
      }
    }
  }
  __syncthreads();

  // stage mlp-out (+b2) into xn, then coalesced residual write
#pragma unroll
  for (int mt = 0; mt < 4; ++mt)
#pragma unroll
    for (int nt = 0; nt < 3; ++nt) {
      int col = wave * 48 + nt * 16 + p;
      float bias = b2[col];
#pragma unroll
      for (int r = 0; r < 4; ++r)
        xn[mt * 16 + q * 4 + r][col] = f2b(accO[mt][nt][r] + bias);
    }
  __syncthreads();

  for (int idx = tid; idx < DIM * 16; idx += 256) {
    int c = idx >> 4, x4 = (idx & 15) * 4;
    size_t base = (((size_t)(b * DIM + c)) << 16) + (y << 8) + x0 + x4;
    u16x4 xm = *(const u16x4*)(x_mid + base);
    float4 o;
    o.x = b2f(xm[0]) + b2f(xn[x4 + 0][c]);
    o.y = b2f(xm[1]) + b2f(xn[x4 + 1][c]);
    o.z = b2f(xm[2]) + b2f(xn[x4 + 2][c]);
    o.w = b2f(xm[3]) + b2f(xn[x4 + 3][c]);
    *(float4*)(out + base) = o;
  }
}

// ---------------- host launcher --------------------------------------------
extern "C" void kernel_launch(void* const* d_in, const int* in_sizes, int n_in,
                              void* d_out, int out_size, void* d_ws, size_t ws_size,
                              hipStream_t stream) {
  const float* x      = (const float*)d_in[0];
  const float* qkv_w  = (const float*)d_in[1];
  const float* qkv_b  = (const float*)d_in[2];
  const float* proj_w = (const float*)d_in[3];
  const float* proj_b = (const float*)d_in[4];
  const float* n1w    = (const float*)d_in[5];
  const float* n1b    = (const float*)d_in[6];
  const float* n2w    = (const float*)d_in[7];
  const float* n2b    = (const float*)d_in[8];
  const float* mlp_w1 = (const float*)d_in[9];
  const float* mlp_b1 = (const float*)d_in[10];
  const float* mlp_w2 = (const float*)d_in[11];
  const float* mlp_b2 = (const float*)d_in[12];
  float* out = (float*)d_out;

  char* ws = (char*)d_ws;
  const size_t XMID_B  = (size_t)4 * DIM * 256 * 256 * 2;     // 100663296
  ushort_t* x_mid = (ushort_t*)ws;
  ushort_t* qkvT  = (ushort_t*)(ws + XMID_B);
  ushort_t* projT = (ushort_t*)(ws + XMID_B + 221184);
  ushort_t* w1T   = (ushort_t*)(ws + XMID_B + 221184 + 73728);
  ushort_t* w2T   = (ushort_t*)(ws + XMID_B + 221184 + 73728 + 294912);
  float* partial  = (float*)(ws + XMID_B + 221184 + 73728 + 294912 + 294912);
  float* stats1   = (float*)(ws + XMID_B + 221184 + 73728 + 294912 + 294912 + 16384);
  float* stats2   = (float*)(ws + XMID_B + 221184 + 73728 + 294912 + 294912 + 16384 + 256);

  transpose_w<<<(576 * 192 + 255) / 256, 256, 0, stream>>>(qkv_w, qkvT, 192, 576);
  transpose_w<<<(192 * 192 + 255) / 256, 256, 0, stream>>>(proj_w, projT, 192, 192);
  transpose_w<<<(768 * 192 + 255) / 256, 256, 0, stream>>>(mlp_w1, w1T, 192, 768);
  transpose_w<<<(192 * 768 + 255) / 256, 256, 0, stream>>>(mlp_w2, w2T, 768, 192);

  gn_stats1_f32<<<32 * 64, 256, 0, stream>>>(x, partial);
  gn_stats2<<<32, 64, 0, stream>>>(partial, stats1);

  attn_kernel<<<NWIN, 384, 0, stream>>>(x, qkvT, qkv_b, projT, proj_b,
                                        stats1, n1w, n1b, x_mid);

  gn_stats1_bf16<<<32 * 64, 256, 0, stream>>>(x_mid, partial);
  gn_stats2<<<32, 64, 0, stream>>>(partial, stats2);

  mlp_kernel<<<NWIN, 256, 0, stream>>>(x_mid, w1T, mlp_b1, w2T, mlp_b2,
                                       stats2, n2w, n2b, out);
}

// Round 3
// 1132.985 us; speedup vs baseline: 1.0976x; 1.0976x over previous
//
#include <hip/hip_runtime.h>

typedef unsigned short ushort_t;
typedef __bf16 bf16x8 __attribute__((ext_vector_type(8)));
typedef float f32x4 __attribute__((ext_vector_type(4)));
typedef unsigned short u16x8 __attribute__((ext_vector_type(8)));
typedef unsigned short u16x4 __attribute__((ext_vector_type(4)));

#define MFMA16(a, b, c) __builtin_amdgcn_mfma_f32_16x16x32_bf16(a, b, c, 0, 0, 0)

#define DIM 192
#define HEADS 6
#define GROUPS 8
#define CPG 24
#define HID 768
#define NWIN 4096
#define GN_N 1572864
#define SCALE 0.17677669529663687f

__device__ __forceinline__ ushort_t f2b(float f) {
  union { float f; unsigned int u; } v; v.f = f;
  unsigned int r = v.u + 0x7FFFu + ((v.u >> 16) & 1u);
  return (ushort_t)(r >> 16);
}
__device__ __forceinline__ float b2f(ushort_t u) {
  union { unsigned int u; float f; } v; v.u = ((unsigned int)u) << 16;
  return v.f;
}

// ---------------- weight transpose + bf16 convert: out[n][k] = in[k][n] ----
__global__ __launch_bounds__(256) void transpose_w(const float* __restrict__ in,
                                                   ushort_t* __restrict__ out,
                                                   int K, int N) {
  int id = blockIdx.x * 256 + threadIdx.x;
  if (id >= K * N) return;
  int n = id / K, k = id - n * K;
  out[id] = f2b(in[k * N + n]);
}

// ---------------- GroupNorm stats for x (fp32), stage 1 --------------------
__global__ __launch_bounds__(256) void gn_stats1_f32(const float* __restrict__ x,
                                                     float* __restrict__ partial) {
  int bid = blockIdx.x;           // 32 * 64
  int sg = bid >> 6, chunk = bid & 63;
  const float* p = x + (size_t)sg * GN_N + (size_t)chunk * 24576;
  int tid = threadIdx.x;
  float s = 0.f, s2 = 0.f;
#pragma unroll
  for (int i = 0; i < 24; ++i) {
    float4 v = *(const float4*)(p + (size_t)(i * 256 + tid) * 4);
    s += v.x + v.y + v.z + v.w;
    s2 += v.x * v.x + v.y * v.y + v.z * v.z + v.w * v.w;
  }
  for (int m = 1; m < 64; m <<= 1) { s += __shfl_xor(s, m); s2 += __shfl_xor(s2, m); }
  __shared__ float red[8];
  int wv = tid >> 6;
  if ((tid & 63) == 0) { red[wv * 2] = s; red[wv * 2 + 1] = s2; }
  __syncthreads();
  if (tid == 0) {
    float a = 0.f, b = 0.f;
    for (int i = 0; i < 4; ++i) { a += red[i * 2]; b += red[i * 2 + 1]; }
    partial[bid * 2] = a; partial[bid * 2 + 1] = b;
  }
}

__global__ __launch_bounds__(64) void gn_stats2(const float* __restrict__ partial,
                                                float* __restrict__ stats) {
  int sg = blockIdx.x;
  int lane = threadIdx.x;
  float s = partial[(sg * 64 + lane) * 2];
  float s2 = partial[(sg * 64 + lane) * 2 + 1];
  for (int m = 1; m < 64; m <<= 1) { s += __shfl_xor(s, m); s2 += __shfl_xor(s2, m); }
  if (lane == 0) {
    const float invN = 1.0f / (float)GN_N;
    float mean = s * invN;
    float var = s2 * invN - mean * mean;
    stats[sg * 2] = mean;
    stats[sg * 2 + 1] = rsqrtf(var + 1e-5f);
  }
}

// ---------------- GN2 reduce: per-window partials -> stats -----------------
__global__ __launch_bounds__(64) void gn2_reduce(const float2* __restrict__ gpart,
                                                 float* __restrict__ stats) {
  int bid = blockIdx.x;            // b*8 + g
  int b = bid >> 3, g = bid & 7;
  int lane = threadIdx.x;
  float s = 0.f, s2 = 0.f;
  for (int w = lane; w < 1024; w += 64) {
    float2 v = gpart[((size_t)b * 1024 + w) * 8 + g];
    s += v.x; s2 += v.y;
  }
  for (int m = 1; m < 64; m <<= 1) { s += __shfl_xor(s, m); s2 += __shfl_xor(s2, m); }
  if (lane == 0) {
    const float invN = 1.0f / (float)GN_N;
    float mean = s * invN;
    float var = s2 * invN - mean * mean;
    stats[bid * 2] = mean;
    stats[bid * 2 + 1] = rsqrtf(var + 1e-5f);
  }
}

// ---------------- fused window attention, 12 waves -------------------------
__global__ __launch_bounds__(768, 1) void attn_kernel(
    const float* __restrict__ x,
    const ushort_t* __restrict__ qkvT, const float* __restrict__ qkv_b,
    const ushort_t* __restrict__ projT, const float* __restrict__ proj_b,
    const float* __restrict__ stats1,
    const float* __restrict__ n1w, const float* __restrict__ n1b,
    ushort_t* __restrict__ x_mid, float2* __restrict__ gpart) {
  int w = blockIdx.x;
  int b = w >> 10, wh = (w >> 5) & 31, ww = w & 31;
  int tid = threadIdx.x;
  int wave = tid >> 6, lane = tid & 63;
  int p = lane & 15, q = lane >> 4;

  __shared__ ushort_t tile[64][200];    // xn -> O -> proj-out
  __shared__ ushort_t qkP[6][5120];     // per head: q[64][40] | k[64][40] -> P[64][72]; later resid
  __shared__ ushort_t vT[6][2304];      // per head: v^T [32][72]; later stats red

  // ---- phase 0: gather + groupnorm + roll into tile[token][c] ----
  for (int u = tid; u < 1536; u += 768) {
    int c = u >> 3, i = u & 7;
    int g = c / CPG;
    float mean = stats1[(b * 8 + g) * 2], rstd = stats1[(b * 8 + g) * 2 + 1];
    float gw = n1w[c] * rstd;
    float gb = n1b[c] - mean * gw;
    int py = ((wh << 3) + i + 4) & 255;
    const float* src = x + (((size_t)(b * DIM + c)) << 16) + (py << 8);
    int px0 = (ww << 3) + 4;
    int px1 = (px0 + 4) & 255;
    float4 ra = *(const float4*)(src + px0);
    float4 rb = *(const float4*)(src + px1);
    int t0 = i * 8;
    tile[t0 + 0][c] = f2b(ra.x * gw + gb);
    tile[t0 + 1][c] = f2b(ra.y * gw + gb);
    tile[t0 + 2][c] = f2b(ra.z * gw + gb);
    tile[t0 + 3][c] = f2b(ra.w * gw + gb);
    tile[t0 + 4][c] = f2b(rb.x * gw + gb);
    tile[t0 + 5][c] = f2b(rb.y * gw + gb);
    tile[t0 + 6][c] = f2b(rb.z * gw + gb);
    tile[t0 + 7][c] = f2b(rb.w * gw + gb);
  }
  __syncthreads();   // B1

  // ---- phase 1: qkv GEMM, each wave 48 cols; sec uniform per wave ----
  {
    int colbase = wave * 48;
    int sec = wave >> 2;              // 0=q, 1=k, 2=v
    f32x4 acc[3][4];
#pragma unroll
    for (int nt = 0; nt < 3; ++nt)
#pragma unroll
      for (int mt = 0; mt < 4; ++mt) acc[nt][mt] = (f32x4){0.f, 0.f, 0.f, 0.f};
#pragma unroll
    for (int ks = 0; ks < 6; ++ks) {
      int k0 = ks * 32 + q * 8;
      bf16x8 afr[4];
#pragma unroll
      for (int mt = 0; mt < 4; ++mt) afr[mt] = *(const bf16x8*)&tile[mt * 16 + p][k0];
#pragma unroll
      for (int nt = 0; nt < 3; ++nt) {
        bf16x8 bfr = *(const bf16x8*)(qkvT + (size_t)(colbase + nt * 16 + p) * DIM + k0);
#pragma unroll
        for (int mt = 0; mt < 4; ++mt) acc[nt][mt] = MFMA16(afr[mt], bfr, acc[nt][mt]);
      }
    }
#pragma unroll
    for (int nt = 0; nt < 3; ++nt) {
      int col = colbase + nt * 16 + p;
      float bias = qkv_b[col];
      int hc = col - sec * DIM;
      int h = hc >> 5, d = hc & 31;
      if (sec == 0) {
#pragma unroll
        for (int mt = 0; mt < 4; ++mt)
#pragma unroll
          for (int r = 0; r < 4; ++r)
            qkP[h][(mt * 16 + q * 4 + r) * 40 + d] = f2b((acc[nt][mt][r] + bias) * SCALE);
      } else if (sec == 1) {
#pragma unroll
        for (int mt = 0; mt < 4; ++mt)
#pragma unroll
          for (int r = 0; r < 4; ++r)
            qkP[h][2560 + (mt * 16 + q * 4 + r) * 40 + d] = f2b(acc[nt][mt][r] + bias);
      } else {
#pragma unroll
        for (int mt = 0; mt < 4; ++mt) {
          u16x4 vv;
#pragma unroll
          for (int r = 0; r < 4; ++r) vv[r] = f2b(acc[nt][mt][r] + bias);
          *(u16x4*)&vT[h][d * 72 + mt * 16 + q * 4] = vv;
        }
      }
    }
  }
  __syncthreads();   // B2

  // ---- phase 2: attention; wave-pair per head ----
  {
    int h = wave >> 1, half = wave & 1;
    const ushort_t* qh = &qkP[h][0];
    const ushort_t* kh = &qkP[h][2560];
    int k0 = q * 8;
    bf16x8 aq[2], bk[4];
#pragma unroll
    for (int m2 = 0; m2 < 2; ++m2)
      aq[m2] = *(const bf16x8*)&qh[((half * 2 + m2) * 16 + p) * 40 + k0];
#pragma unroll
    for (int nt = 0; nt < 4; ++nt)
      bk[nt] = *(const bf16x8*)&kh[(nt * 16 + p) * 40 + k0];
    f32x4 s[2][4];
#pragma unroll
    for (int m2 = 0; m2 < 2; ++m2)
#pragma unroll
      for (int nt = 0; nt < 4; ++nt) {
        s[m2][nt] = (f32x4){0.f, 0.f, 0.f, 0.f};
        s[m2][nt] = MFMA16(aq[m2], bk[nt], s[m2][nt]);
      }
    __syncthreads();   // B3: all q/k reads done before P overwrites the region

    ushort_t* Ph = &qkP[h][0];
#pragma unroll
    for (int m2 = 0; m2 < 2; ++m2)
#pragma unroll
      for (int r = 0; r < 4; ++r) {
        float m = fmaxf(fmaxf(s[m2][0][r], s[m2][1][r]), fmaxf(s[m2][2][r], s[m2][3][r]));
        for (int msk = 1; msk < 16; msk <<= 1) m = fmaxf(m, __shfl_xor(m, msk));
        float e0 = __expf(s[m2][0][r] - m);
        float e1 = __expf(s[m2][1][r] - m);
        float e2 = __expf(s[m2][2][r] - m);
        float e3 = __expf(s[m2][3][r] - m);
        float sum = e0 + e1 + e2 + e3;
        for (int msk = 1; msk < 16; msk <<= 1) sum += __shfl_xor(sum, msk);
        float inv = 1.0f / sum;
        int row = (half * 2 + m2) * 16 + q * 4 + r;
        Ph[row * 72 + 0 * 16 + p] = f2b(e0 * inv);
        Ph[row * 72 + 1 * 16 + p] = f2b(e1 * inv);
        Ph[row * 72 + 2 * 16 + p] = f2b(e2 * inv);
        Ph[row * 72 + 3 * 16 + p] = f2b(e3 * inv);
      }
    // PV: rows of own half
    f32x4 o[2][2];
#pragma unroll
    for (int m2 = 0; m2 < 2; ++m2)
#pragma unroll
      for (int nt = 0; nt < 2; ++nt) o[m2][nt] = (f32x4){0.f, 0.f, 0.f, 0.f};
#pragma unroll
    for (int ks = 0; ks < 2; ++ks) {
      int kk = ks * 32 + q * 8;
      bf16x8 bv[2];
#pragma unroll
      for (int nt = 0; nt < 2; ++nt) bv[nt] = *(const bf16x8*)&vT[h][(nt * 16 + p) * 72 + kk];
#pragma unroll
      for (int m2 = 0; m2 < 2; ++m2) {
        bf16x8 ap = *(const bf16x8*)&Ph[((half * 2 + m2) * 16 + p) * 72 + kk];
#pragma unroll
        for (int nt = 0; nt < 2; ++nt) o[m2][nt] = MFMA16(ap, bv[nt], o[m2][nt]);
      }
    }
#pragma unroll
    for (int m2 = 0; m2 < 2; ++m2)
#pragma unroll
      for (int nt = 0; nt < 2; ++nt)
#pragma unroll
        for (int r = 0; r < 4; ++r)
          tile[(half * 2 + m2) * 16 + q * 4 + r][h * 32 + nt * 16 + p] = f2b(o[m2][nt][r]);
  }
  __syncthreads();   // B4

  // ---- phase 3: proj GEMM, 16 cols per wave ----
  {
    int col = wave * 16 + p;
    f32x4 pr[4];
#pragma unroll
    for (int mt = 0; mt < 4; ++mt) pr[mt] = (f32x4){0.f, 0.f, 0.f, 0.f};
#pragma unroll
    for (int ks = 0; ks < 6; ++ks) {
      int k0 = ks * 32 + q * 8;
      bf16x8 bfr = *(const bf16x8*)(projT + (size_t)col * DIM + k0);
#pragma unroll
      for (int mt = 0; mt < 4; ++mt) {
        bf16x8 afr = *(const bf16x8*)&tile[mt * 16 + p][k0];
        pr[mt] = MFMA16(afr, bfr, pr[mt]);
      }
    }
    __syncthreads();   // B5: all tile reads done
    float bias = proj_b[col];
#pragma unroll
    for (int mt = 0; mt < 4; ++mt)
#pragma unroll
      for (int r = 0; r < 4; ++r)
        tile[mt * 16 + q * 4 + r][col] = f2b(pr[mt][r] + bias);
  }
  __syncthreads();   // B6

  // ---- epilogue a: residual-1 into resid (qkP region), channel-major ----
  ushort_t* resid = &qkP[0][0];       // [64][200]
  for (int u = tid; u < 1536; u += 768) {
    int c = u >> 3, i = u & 7;
    int py = ((wh << 3) + i + 4) & 255;
    const float* src = x + (((size_t)(b * DIM + c)) << 16) + (py << 8);
    int px0 = (ww << 3) + 4;
    int px1 = (px0 + 4) & 255;
    float4 ra = *(const float4*)(src + px0);
    float4 rb = *(const float4*)(src + px1);
    int t0 = i * 8;
    resid[(t0 + 0) * 200 + c] = f2b(ra.x + b2f(tile[t0 + 0][c]));
    resid[(t0 + 1) * 200 + c] = f2b(ra.y + b2f(tile[t0 + 1][c]));
    resid[(t0 + 2) * 200 + c] = f2b(ra.z + b2f(tile[t0 + 2][c]));
    resid[(t0 + 3) * 200 + c] = f2b(ra.w + b2f(tile[t0 + 3][c]));
    resid[(t0 + 4) * 200 + c] = f2b(rb.x + b2f(tile[t0 + 4][c]));
    resid[(t0 + 5) * 200 + c] = f2b(rb.y + b2f(tile[t0 + 5][c]));
    resid[(t0 + 6) * 200 + c] = f2b(rb.z + b2f(tile[t0 + 6][c]));
    resid[(t0 + 7) * 200 + c] = f2b(rb.w + b2f(tile[t0 + 7][c]));
  }
  __syncthreads();   // B7

  // ---- epilogue b: coalesced x_mid write (windowed) + per-unit stats ----
  float2* red = (float2*)&vT[0][0];   // 1536 float2 = 12 KB
  ushort_t* xmw = x_mid + (size_t)w * 12288;
  for (int u = tid; u < 1536; u += 768) {
    int token = u / 24, ch = u - token * 24;
    int c8 = ch * 8;
    u16x8 v = *(const u16x8*)&resid[token * 200 + c8];
    *(u16x8*)&xmw[token * 192 + c8] = v;
    float s = 0.f, s2 = 0.f;
#pragma unroll
    for (int t = 0; t < 8; ++t) { float f = b2f(v[t]); s += f; s2 += f * f; }
    red[u] = make_float2(s, s2);
  }
  __syncthreads();   // B8

  if (wave < 8) {
    int g = wave;
    float s = 0.f, s2 = 0.f;
#pragma unroll
    for (int j = 0; j < 3; ++j) {
      float2 t = red[lane * 24 + g * 3 + j];
      s += t.x; s2 += t.y;
    }
    for (int m = 1; m < 64; m <<= 1) { s += __shfl_xor(s, m); s2 += __shfl_xor(s2, m); }
    if (lane == 0) gpart[(size_t)w * 8 + g] = make_float2(s, s2);
  }
}

// ---------------- fused GN2 + MLP + residual2 ------------------------------
// one block per (b, y, 64-px quarter); reads windowed x_mid.
// windowed token (i,j) of window (wh,ww) holds ORIGINAL pixel
// y=(wh*8+i+4)&255, x=(ww*8+j+4)&255  =>  inverse: s=(orig-4)&255.
__global__ __launch_bounds__(256) void mlp_kernel(
    const ushort_t* __restrict__ x_mid,
    const ushort_t* __restrict__ w1T, const float* __restrict__ b1,
    const ushort_t* __restrict__ w2T, const float* __restrict__ b2,
    const float* __restrict__ stats2,
    const float* __restrict__ n2w, const float* __restrict__ n2b,
    float* __restrict__ out) {
  int bid = blockIdx.x;
  int b = bid >> 10, y = (bid >> 2) & 255, xq = bid & 3;
  int x0 = xq * 64;
  int tid = threadIdx.x;
  int wave = tid >> 6, lane = tid & 63;
  int p = lane & 15, q = lane >> 4;

  __shared__ ushort_t xn[64][200];   // xn tile (pixel-major), later staging
  __shared__ ushort_t hb[64][72];    // hidden chunk

  int yp = (y + 252) & 255;          // (y - 4) mod 256
  int whp = yp >> 3, ip = yp & 7;
  size_t winrow = ((size_t)b * 1024 + (size_t)whp * 32) * 12288;

  for (int u = tid; u < 1536; u += 256) {
    int tx = u / 24, ch = u - tx * 24;
    int c8 = ch * 8;
    int xp = (x0 + tx + 252) & 255;  // (x - 4) mod 256
    int g = ch / 3;
    float mean = stats2[(b * 8 + g) * 2], rstd = stats2[(b * 8 + g) * 2 + 1];
    u16x8 v = *(const u16x8*)(x_mid + winrow + (size_t)(xp >> 3) * 12288 +
                              (size_t)(ip * 8 + (xp & 7)) * 192 + c8);
    u16x8 o;
#pragma unroll
    for (int t = 0; t < 8; ++t) {
      int c = c8 + t;
      float gw = n2w[c] * rstd;
      float gb = n2b[c] - mean * gw;
      o[t] = f2b(b2f(v[t]) * gw + gb);
    }
    *(u16x8*)&xn[tx][c8] = o;
  }
  __syncthreads();

  f32x4 accO[4][3];
#pragma unroll
  for (int mt = 0; mt < 4; ++mt)
#pragma unroll
    for (int nt = 0; nt < 3; ++nt) accO[mt][nt] = (f32x4){0.f, 0.f, 0.f, 0.f};

  for (int ch = 0; ch < 12; ++ch) {
    int hcol = ch * 64 + wave * 16 + p;
    f32x4 a1[4];
#pragma unroll
    for (int mt = 0; mt < 4; ++mt) a1[mt] = (f32x4){0.f, 0.f, 0.f, 0.f};
#pragma unroll
    for (int ks = 0; ks < 6; ++ks) {
      int k0 = ks * 32 + q * 8;
      bf16x8 bfr = *(const bf16x8*)(w1T + (size_t)hcol * DIM + k0);
#pragma unroll
      for (int mt = 0; mt < 4; ++mt) {
        bf16x8 afr = *(const bf16x8*)&xn[mt * 16 + p][k0];
        a1[mt] = MFMA16(afr, bfr, a1[mt]);
      }
    }
    float bias = b1[hcol];
    if (ch) __syncthreads();
#pragma unroll
    for (int mt = 0; mt < 4; ++mt)
#pragma unroll
      for (int r = 0; r < 4; ++r) {
        float v = a1[mt][r] + bias;
        v = 0.5f * v * (1.0f + erff(v * 0.70710678118654752f));
        hb[mt * 16 + q * 4 + r][wave * 16 + p] = f2b(v);
      }
    __syncthreads();
#pragma unroll
    for (int ks = 0; ks < 2; ++ks) {
      int k0 = ks * 32 + q * 8;
#pragma unroll
      for (int mt = 0; mt < 4; ++mt) {
        bf16x8 afr = *(const bf16x8*)&hb[mt * 16 + p][k0];
#pragma unroll
        for (int nt = 0; nt < 3; ++nt) {
          bf16x8 bfr = *(const bf16x8*)(w2T + (size_t)(wave * 48 + nt * 16 + p) * HID + ch * 64 + k0);
          accO[mt][nt] = MFMA16(afr, bfr, accO[mt][nt]);
        }
      }
    }
  }
  __syncthreads();

#pragma unroll
  for (int mt = 0; mt < 4; ++mt)
#pragma unroll
    for (int nt = 0; nt < 3; ++nt) {
      int col = wave * 48 + nt * 16 + p;
      float bias = b2[col];
#pragma unroll
      for (int r = 0; r < 4; ++r)
        xn[mt * 16 + q * 4 + r][col] = f2b(accO[mt][nt][r] + bias);
    }
  __syncthreads();

  for (int idx = tid; idx < DIM * 16; idx += 256) {
    int c = idx >> 4, x4 = (idx & 15) * 4;
    size_t base = (((size_t)(b * DIM + c)) << 16) + (y << 8) + x0 + x4;
    float4 o;
    float r[4];
#pragma unroll
    for (int j = 0; j < 4; ++j) {
      int xp = (x0 + x4 + j + 252) & 255;   // (x - 4) mod 256
      r[j] = b2f(x_mid[winrow + (size_t)(xp >> 3) * 12288 +
                       (size_t)(ip * 8 + (xp & 7)) * 192 + c]);
    }
    o.x = r[0] + b2f(xn[x4 + 0][c]);
    o.y = r[1] + b2f(xn[x4 + 1][c]);
    o.z = r[2] + b2f(xn[x4 + 2][c]);
    o.w = r[3] + b2f(xn[x4 + 3][c]);
    *(float4*)(out + base) = o;
  }
}

// ---------------- host launcher --------------------------------------------
extern "C" void kernel_launch(void* const* d_in, const int* in_sizes, int n_in,
                              void* d_out, int out_size, void* d_ws, size_t ws_size,
                              hipStream_t stream) {
  const float* x      = (const float*)d_in[0];
  const float* qkv_w  = (const float*)d_in[1];
  const float* qkv_b  = (const float*)d_in[2];
  const float* proj_w = (const float*)d_in[3];
  const float* proj_b = (const float*)d_in[4];
  const float* n1w    = (const float*)d_in[5];
  const float* n1b    = (const float*)d_in[6];
  const float* n2w    = (const float*)d_in[7];
  const float* n2b    = (const float*)d_in[8];
  const float* mlp_w1 = (const float*)d_in[9];
  const float* mlp_b1 = (const float*)d_in[10];
  const float* mlp_w2 = (const float*)d_in[11];
  const float* mlp_b2 = (const float*)d_in[12];
  float* out = (float*)d_out;

  char* ws = (char*)d_ws;
  const size_t XMID_B = (size_t)NWIN * 64 * DIM * 2;          // 100663296
  ushort_t* x_mid = (ushort_t*)ws;
  ushort_t* qkvT  = (ushort_t*)(ws + XMID_B);
  ushort_t* projT = (ushort_t*)(ws + XMID_B + 221184);
  ushort_t* w1T   = (ushort_t*)(ws + XMID_B + 221184 + 73728);
  ushort_t* w2T   = (ushort_t*)(ws + XMID_B + 221184 + 73728 + 294912);
  float* partial  = (float*)(ws + XMID_B + 884736);
  float* stats1   = (float*)(ws + XMID_B + 884736 + 16384);
  float* stats2   = (float*)(ws + XMID_B + 884736 + 16384 + 256);
  float2* gpart   = (float2*)(ws + XMID_B + 884736 + 16384 + 512);

  transpose_w<<<(576 * 192 + 255) / 256, 256, 0, stream>>>(qkv_w, qkvT, 192, 576);
  transpose_w<<<(192 * 192 + 255) / 256, 256, 0, stream>>>(proj_w, projT, 192, 192);
  transpose_w<<<(768 * 192 + 255) / 256, 256, 0, stream>>>(mlp_w1, w1T, 192, 768);
  transpose_w<<<(192 * 768 + 255) / 256, 256, 0, stream>>>(mlp_w2, w2T, 768, 192);

  gn_stats1_f32<<<32 * 64, 256, 0, stream>>>(x, partial);
  gn_stats2<<<32, 64, 0, stream>>>(partial, stats1);

  attn_kernel<<<NWIN, 768, 0, stream>>>(x, qkvT, qkv_b, projT, proj_b,
                                        stats1, n1w, n1b, x_mid, gpart);

  gn2_reduce<<<32, 64, 0, stream>>>(gpart, stats2);

  mlp_kernel<<<NWIN, 256, 0, stream>>>(x_mid, w1T, mlp_b1, w2T, mlp_b2,
                                       stats2, n2w, n2b, out);
}